// Round 23
// baseline (76.712 us; speedup 1.0000x reference)
//
#include <hip/hip_runtime.h>
#include <hip/hip_bf16.h>

#define NEL 16384

// ---- workspace layout (offsets in SHORTS from d_ws base) ----
#define W1B_OFF 0                         // bf16 W1 [128][64]
#define W2B_OFF 8192                      // bf16 W2 [128][128]
#define W3B_OFF 24576                     // bf16 W3 [512][128]
#define WS_WEIGHTS 90112
#define S1_OFF  90112                     // bf16 [NEL][128]
#define S2_OFF  (S1_OFF + NEL*128)
#define Z2_OFF  (S2_OFF + NEL*128)        // (unused slot, kept for layout stability)
#define V_OFF   (Z2_OFF + NEL*128)        // bf16 [NEL][512]
#define DZ2_OFF (V_OFF + NEL*512)         // bf16 [NEL*8][128]  (row m = e*8+j)

typedef __attribute__((ext_vector_type(8))) short bf16x8;
typedef __attribute__((ext_vector_type(4))) float f32x4;

__device__ __forceinline__ float bf2f(unsigned int u16) {
    unsigned int x = u16 << 16;
    float f; __builtin_memcpy(&f, &x, 4); return f;
}
__device__ __forceinline__ unsigned short f2bf(float f) {
    unsigned int x; __builtin_memcpy(&x, &f, 4);
    x = (x + 0x7FFFu + ((x >> 16) & 1u)) >> 16;
    return (unsigned short)x;
}
__device__ __forceinline__ void unpack8(uint4 q, float* f) {
    f[0] = bf2f(q.x & 0xFFFFu); f[1] = bf2f(q.x >> 16);
    f[2] = bf2f(q.y & 0xFFFFu); f[3] = bf2f(q.y >> 16);
    f[4] = bf2f(q.z & 0xFFFFu); f[5] = bf2f(q.z >> 16);
    f[6] = bf2f(q.w & 0xFFFFu); f[7] = bf2f(q.w >> 16);
}
__device__ __forceinline__ void sp_sig(float x, float& sp, float& sig) {
    float t = __expf(-fabsf(x));
    float r = __builtin_amdgcn_rcpf(1.f + t);
    sig = (x >= 0.f) ? r : 1.f - r;
    sp  = fmaxf(x, 0.f) + __logf(1.f + t);
}
__device__ __forceinline__ float tanh_fast(float x) {
    float t = __expf(-2.f * fabsf(x));
    float y = (1.f - t) * __builtin_amdgcn_rcpf(1.f + t);
    unsigned int xb, yb;
    __builtin_memcpy(&xb, &x, 4);
    __builtin_memcpy(&yb, &y, 4);
    yb |= (xb & 0x80000000u);
    float rr; __builtin_memcpy(&rr, &yb, 4);
    return rr;
}
__device__ __forceinline__ bf16x8 ldfrag(const unsigned short* p) {
    return *reinterpret_cast<const bf16x8*>(p);
}
__device__ __forceinline__ void cpu4(unsigned short* dst, const unsigned short* src) {
    *reinterpret_cast<uint4*>(dst) = *reinterpret_cast<const uint4*>(src);
}

// ---- prep: bf16 copies of W1, W2, W3 in [out][k] layout ----
__global__ void prep_weights(const float* __restrict__ W1,
                             const float* __restrict__ W2,
                             const float* __restrict__ W3,
                             unsigned short* __restrict__ wb) {
    int i = blockIdx.x * blockDim.x + threadIdx.x;
    if (i >= WS_WEIGHTS) return;
    float v;
    if (i < W2B_OFF) v = W1[i];
    else if (i < W3B_OFF) v = W2[i - W2B_OFF];
    else v = W3[i - W3B_OFF];
    wb[i] = f2bf(v);
}

// ============ K12: fwd1 + fwd2 (staged) + fwd3 (double-buffered 8x64-col, R22 proven) ============
#define K12_LDS 39168
__global__ __launch_bounds__(256, 4)
void k12_fwd(const float* __restrict__ hg,
             const float* __restrict__ b1,
             const float* __restrict__ b2,
             const float* __restrict__ b3,
             unsigned short* __restrict__ wsb) {
    __shared__ __align__(16) char sm[K12_LDS];
    unsigned short* w1s  = (unsigned short*)(sm);           // [128][72]  phase1
    unsigned short* hs   = (unsigned short*)(sm + 18432);   // [16][72]   phase1
    unsigned short* w2s  = (unsigned short*)(sm);           // [128][136] phase2 (overlay)
    unsigned short* wcb0 = (unsigned short*)(sm);           // [64][136]  fwd3 dbuf 0
    unsigned short* wcb1 = (unsigned short*)(sm + 17408);   // [64][136]  fwd3 dbuf 1
    unsigned short* z1s  = (unsigned short*)(sm + 34816);   // [16][136]
    unsigned short* z2s  = (unsigned short*)(sm + 34816);   // [16][136] overlays z1s
    unsigned short* S1g = wsb + S1_OFF;
    unsigned short* S2g = wsb + S2_OFF;
    unsigned short* Vg  = wsb + V_OFF;

    const int tid = threadIdx.x;
    const int e0 = blockIdx.x * 16;
    const int lane = tid & 63;
    const int w = tid >> 6;
    const int r16 = lane & 15;
    const int kb = lane >> 4;
    const int crow = kb * 4;

    #pragma unroll
    for (int q = 0; q < 4; ++q) {
        int idx = q * 256 + tid;
        int row = idx >> 3, u4 = idx & 7;
        cpu4(&w1s[row * 72 + u4 * 8], &wsb[W1B_OFF + row * 64 + u4 * 8]);
    }
    {
        int row = tid >> 4, f4 = tid & 15;
        float4 hv = *reinterpret_cast<const float4*>(&hg[(e0 + row) * 64 + f4 * 4]);
        ushort2 lo = { f2bf(hv.x), f2bf(hv.y) };
        ushort2 hi = { f2bf(hv.z), f2bf(hv.w) };
        *reinterpret_cast<ushort2*>(&hs[row * 72 + f4 * 4]) = lo;
        *reinterpret_cast<ushort2*>(&hs[row * 72 + f4 * 4 + 2]) = hi;
    }
    __syncthreads();

    // fwd1: M=16 N=128 K=64
    {
        const unsigned short* Ab = hs + r16 * 72 + kb * 8;
        bf16x8 a0 = ldfrag(Ab), a1 = ldfrag(Ab + 32);
        f32x4 acc[2] = {};
        #pragma unroll
        for (int t = 0; t < 2; ++t) {
            int col16 = (w * 2 + t) * 16 + r16;
            const unsigned short* Bb = w1s + col16 * 72 + kb * 8;
            acc[t] = __builtin_amdgcn_mfma_f32_16x16x32_bf16(a0, ldfrag(Bb), acc[t], 0, 0, 0);
            acc[t] = __builtin_amdgcn_mfma_f32_16x16x32_bf16(a1, ldfrag(Bb + 32), acc[t], 0, 0, 0);
        }
        #pragma unroll
        for (int t = 0; t < 2; ++t) {
            int col = (w * 2 + t) * 16 + r16;
            float bb = b1[col];
            #pragma unroll
            for (int rr = 0; rr < 4; ++rr) {
                int e = crow + rr;
                float sp, sg;
                sp_sig(acc[t][rr] + bb, sp, sg);
                z1s[e * 136 + col] = f2bf(sp);
                S1g[(e0 + e) * 128 + col] = f2bf(sg);
            }
        }
    }
    __syncthreads();

    #pragma unroll
    for (int q = 0; q < 8; ++q) {
        int idx = q * 256 + tid;
        int row = idx >> 4, u4 = idx & 15;
        cpu4(&w2s[row * 136 + u4 * 8], &wsb[W2B_OFF + row * 128 + u4 * 8]);
    }
    __syncthreads();

    // fwd2: race-protected overlay (A-frags held in regs behind barrier)
    {
        const unsigned short* Ab = z1s + r16 * 136 + kb * 8;
        bf16x8 a[4];
        #pragma unroll
        for (int ks = 0; ks < 4; ++ks) a[ks] = ldfrag(Ab + ks * 32);
        __syncthreads();
        f32x4 acc[2] = {};
        #pragma unroll
        for (int t = 0; t < 2; ++t) {
            int col16 = (w * 2 + t) * 16 + r16;
            const unsigned short* Bb = w2s + col16 * 136 + kb * 8;
            #pragma unroll
            for (int ks = 0; ks < 4; ++ks)
                acc[t] = __builtin_amdgcn_mfma_f32_16x16x32_bf16(a[ks], ldfrag(Bb + ks * 32), acc[t], 0, 0, 0);
        }
        #pragma unroll
        for (int t = 0; t < 2; ++t) {
            int col = (w * 2 + t) * 16 + r16;
            float bb = b2[col];
            #pragma unroll
            for (int rr = 0; rr < 4; ++rr) {
                int e = crow + rr;
                float sp, sg;
                sp_sig(acc[t][rr] + bb, sp, sg);
                z2s[e * 136 + col] = f2bf(sp);
                S2g[(e0 + e) * 128 + col] = f2bf(sg);
            }
        }
    }
    __syncthreads();   // z2s complete; all w2s reads done

    // fwd3: 8 chunks of 64 cols, double-buffered W3 staging
    {
        #pragma unroll
        for (int q = 0; q < 4; ++q) {
            int idx = q * 256 + tid;
            int row = idx >> 4, u4 = idx & 15;
            cpu4(&wcb0[row * 136 + u4 * 8], &wsb[W3B_OFF + row * 128 + u4 * 8]);
        }
        __syncthreads();

        const unsigned short* Ab = z2s + r16 * 136 + kb * 8;
        bf16x8 a[4];
        #pragma unroll
        for (int ks = 0; ks < 4; ++ks) a[ks] = ldfrag(Ab + ks * 32);

        for (int c = 0; c < 8; ++c) {
            unsigned short* cur = (c & 1) ? wcb1 : wcb0;
            unsigned short* nxt = (c & 1) ? wcb0 : wcb1;
            if (c < 7) {
                #pragma unroll
                for (int q = 0; q < 4; ++q) {
                    int idx = q * 256 + tid;
                    int row = idx >> 4, u4 = idx & 15;
                    cpu4(&nxt[row * 136 + u4 * 8], &wsb[W3B_OFF + ((c + 1) * 64 + row) * 128 + u4 * 8]);
                }
            }
            int col = c * 64 + w * 16 + r16;
            const unsigned short* Bb = cur + (w * 16 + r16) * 136 + kb * 8;
            f32x4 acc = {};
            #pragma unroll
            for (int ks = 0; ks < 4; ++ks)
                acc = __builtin_amdgcn_mfma_f32_16x16x32_bf16(a[ks], ldfrag(Bb + ks * 32), acc, 0, 0, 0);
            float bb = b3[col];
            #pragma unroll
            for (int rr = 0; rr < 4; ++rr) {
                int e = crow + rr;
                Vg[(e0 + e) * 512 + col] = f2bf(tanh_fast(acc[rr] + bb));
            }
            __syncthreads();
        }
    }
}

// ============ K3: T-build + jvp1 + jvp2 (staged W2 halves + T14 async split for half 1) ============
#define K3_LDS 35968
__global__ __launch_bounds__(256, 4)
void k3_jvp12(const float* __restrict__ sigg,
              unsigned short* __restrict__ wsb) {
    __shared__ __align__(16) char sm[K3_LDS];
    unsigned short* w1s  = (unsigned short*)(sm);           // [128][72]   phase A
    unsigned short* ts   = (unsigned short*)(sm + 18432);   // [64][72]    phase A
    float*          sigsm= (float*)(sm + 34816);            // [288]       phase A
    unsigned short* dz1s = (unsigned short*)(sm);           // [64][136]   phase B
    unsigned short* w2sh = (unsigned short*)(sm + 17408);   // [64][136]   phase B (half)
    const unsigned short* S1g = wsb + S1_OFF;
    const unsigned short* S2g = wsb + S2_OFF;
    const unsigned short* Vg  = wsb + V_OFF;
    unsigned short* DZ2g = wsb + DZ2_OFF;

    const int tid = threadIdx.x;
    const int e0 = blockIdx.x * 8;
    const int lane = tid & 63;
    const int w = tid >> 6;
    const int r16 = lane & 15;
    const int kb = lane >> 4;

    #pragma unroll
    for (int q = 0; q < 4; ++q) {
        int idx = q * 256 + tid;
        int row = idx >> 3, u4 = idx & 7;
        cpu4(&w1s[row * 72 + u4 * 8], &wsb[W1B_OFF + row * 64 + u4 * 8]);
    }
    #pragma unroll
    for (int q = 0; q < 2; ++q) {
        int idx = q * 256 + tid;
        if (idx < 288) sigsm[idx] = sigg[e0 * 36 + idx];
    }
    __syncthreads();   // B1

    // T-build: V direct from global
    {
        int m = tid >> 2, kq = tid & 3;
        int e = m >> 3, j = m & 7;
        float c8[8];
        #pragma unroll
        for (int i = 0; i < 8; ++i) {
            float v = 0.f;
            if (i < j) {
                int p = 7 * i - i * (i - 1) / 2 + (j - i - 1);
                v = sigsm[e * 36 + 8 + p];
            } else if (i > j) {
                int p = 7 * j - j * (j - 1) / 2 + (i - j - 1);
                v = -sigsm[e * 36 + 8 + p];
            }
            c8[i] = v;
        }
        const unsigned short* Vrow = &Vg[(e0 + e) * 512 + kq * 16];
        float acc[16] = {};
        #pragma unroll
        for (int i = 0; i < 8; ++i) {
            uint4 qa = *reinterpret_cast<const uint4*>(Vrow + i * 64);
            uint4 qb = *reinterpret_cast<const uint4*>(Vrow + i * 64 + 8);
            float fa[8], fb[8];
            unpack8(qa, fa); unpack8(qb, fb);
            #pragma unroll
            for (int kk = 0; kk < 8; ++kk) {
                acc[kk]     += c8[i] * fa[kk];
                acc[kk + 8] += c8[i] * fb[kk];
            }
        }
        unsigned short o[16];
        #pragma unroll
        for (int kk = 0; kk < 16; ++kk) o[kk] = f2bf(acc[kk]);
        uint4 qo;
        qo.x = (unsigned int)o[0] | ((unsigned int)o[1] << 16);
        qo.y = (unsigned int)o[2] | ((unsigned int)o[3] << 16);
        qo.z = (unsigned int)o[4] | ((unsigned int)o[5] << 16);
        qo.w = (unsigned int)o[6] | ((unsigned int)o[7] << 16);
        *reinterpret_cast<uint4*>(&ts[m * 72 + kq * 16]) = qo;
        qo.x = (unsigned int)o[8]  | ((unsigned int)o[9]  << 16);
        qo.y = (unsigned int)o[10] | ((unsigned int)o[11] << 16);
        qo.z = (unsigned int)o[12] | ((unsigned int)o[13] << 16);
        qo.w = (unsigned int)o[14] | ((unsigned int)o[15] << 16);
        *reinterpret_cast<uint4*>(&ts[m * 72 + kq * 16 + 8]) = qo;
    }
    __syncthreads();   // B2

    // jvp1 -> registers
    float dz1v[8][4];
    const int rbase = w * 16 + kb * 4;
    const int e_loc = rbase >> 3;
    {
        const unsigned short* Ab = ts + (w * 16 + r16) * 72 + kb * 8;
        bf16x8 a0 = ldfrag(Ab), a1 = ldfrag(Ab + 32);
        f32x4 acc[8] = {};
        #pragma unroll
        for (int nt = 0; nt < 8; ++nt) {
            const unsigned short* Bb = w1s + (nt * 16 + r16) * 72 + kb * 8;
            acc[nt] = __builtin_amdgcn_mfma_f32_16x16x32_bf16(a0, ldfrag(Bb), acc[nt], 0, 0, 0);
            acc[nt] = __builtin_amdgcn_mfma_f32_16x16x32_bf16(a1, ldfrag(Bb + 32), acc[nt], 0, 0, 0);
        }
        #pragma unroll
        for (int nt = 0; nt < 8; ++nt) {
            int col = nt * 16 + r16;
            float s1v = bf2f(S1g[(e0 + e_loc) * 128 + col]);
            #pragma unroll
            for (int rr = 0; rr < 4; ++rr)
                dz1v[nt][rr] = acc[nt][rr] * s1v;
        }
    }
    __syncthreads();   // B3

    // Phase B: write dz1s; stage W2 half 0
    #pragma unroll
    for (int nt = 0; nt < 8; ++nt) {
        int col = nt * 16 + r16;
        #pragma unroll
        for (int rr = 0; rr < 4; ++rr)
            dz1s[(rbase + rr) * 136 + col] = f2bf(dz1v[nt][rr]);
    }
    #pragma unroll
    for (int q = 0; q < 4; ++q) {
        int idx = q * 256 + tid;
        int row = idx >> 4, u4 = idx & 15;
        cpu4(&w2sh[row * 136 + u4 * 8], &wsb[W2B_OFF + row * 128 + u4 * 8]);
    }
    __syncthreads();   // B4

    // T14 async-STAGE split: issue W2 half-1 loads into registers NOW;
    // latency hides under jvp2 half-0 compute. Written to LDS after B5.
    uint4 w2r[4];
    #pragma unroll
    for (int q = 0; q < 4; ++q) {
        int idx = q * 256 + tid;
        int row = idx >> 4, u4 = idx & 15;
        w2r[q] = *reinterpret_cast<const uint4*>(&wsb[W2B_OFF + (64 + row) * 128 + u4 * 8]);
    }

    bf16x8 a2[4];
    {
        const unsigned short* Ab = dz1s + (w * 16 + r16) * 136 + kb * 8;
        #pragma unroll
        for (int ks = 0; ks < 4; ++ks) a2[ks] = ldfrag(Ab + ks * 32);
    }

    // jvp2 half 0
    {
        f32x4 acc[4] = {};
        #pragma unroll
        for (int nt = 0; nt < 4; ++nt) {
            const unsigned short* Bb = w2sh + (nt * 16 + r16) * 136 + kb * 8;
            #pragma unroll
            for (int ks = 0; ks < 4; ++ks)
                acc[nt] = __builtin_amdgcn_mfma_f32_16x16x32_bf16(a2[ks], ldfrag(Bb + ks * 32), acc[nt], 0, 0, 0);
        }
        #pragma unroll
        for (int nt = 0; nt < 4; ++nt) {
            int col = nt * 16 + r16;
            float s2v = bf2f(S2g[(e0 + e_loc) * 128 + col]);
            #pragma unroll
            for (int rr = 0; rr < 4; ++rr)
                DZ2g[(e0 * 8 + rbase + rr) * 128 + col] = f2bf(acc[nt][rr] * s2v);
        }
    }
    __syncthreads();   // B5: half-0 reads of w2sh complete

    // write-late: spill the register-held half-1 into LDS (no global latency here)
    #pragma unroll
    for (int q = 0; q < 4; ++q) {
        int idx = q * 256 + tid;
        int row = idx >> 4, u4 = idx & 15;
        *reinterpret_cast<uint4*>(&w2sh[row * 136 + u4 * 8]) = w2r[q];
    }
    __syncthreads();   // B6

    // jvp2 half 1
    {
        f32x4 acc[4] = {};
        #pragma unroll
        for (int nt = 0; nt < 4; ++nt) {
            const unsigned short* Bb = w2sh + (nt * 16 + r16) * 136 + kb * 8;
            #pragma unroll
            for (int ks = 0; ks < 4; ++ks)
                acc[nt] = __builtin_amdgcn_mfma_f32_16x16x32_bf16(a2[ks], ldfrag(Bb + ks * 32), acc[nt], 0, 0, 0);
        }
        #pragma unroll
        for (int nt = 0; nt < 4; ++nt) {
            int col = 64 + nt * 16 + r16;
            float s2v = bf2f(S2g[(e0 + e_loc) * 128 + col]);
            #pragma unroll
            for (int rr = 0; rr < 4; ++rr)
                DZ2g[(e0 * 8 + rbase + rr) * 128 + col] = f2bf(acc[nt][rr] * s2v);
        }
    }
}

// ============ K4: jvp3, WAVE-AUTONOMOUS (j = w, w+4), barrier-free loop (R18 proven) ============
#define K4_LDS (16384 + 576)
__global__ __launch_bounds__(256, 4)
void k4_jvp3(const float* __restrict__ sigg,
             const unsigned short* __restrict__ wsb,
             float* __restrict__ out) {
    __shared__ __align__(16) char sm[K4_LDS];
    float* part = (float*)sm;               // [4][16][64]
    float* sg1  = (float*)(sm + 16384);     // [16][9]
    const unsigned short* Vg = wsb + V_OFF;
    const unsigned short* DZ2g = wsb + DZ2_OFF;

    const int tid = threadIdx.x;
    const int e0 = blockIdx.x * 16;
    const int lane = tid & 63;
    const int w = tid >> 6;
    const int r16 = lane & 15;
    const int kb = lane >> 4;
    const int crow = kb * 4;

    if (tid < 128) {
        int e = tid >> 3, j7 = tid & 7;
        sg1[e * 9 + j7] = sigg[(e0 + e) * 36 + j7];
    }
    __syncthreads();

    float oacc[4][4] = {};

    #pragma unroll
    for (int jj = 0; jj < 2; ++jj) {
        int j = w + jj * 4;
        const unsigned short* Ag = DZ2g + ((e0 + r16) * 8 + j) * 128 + kb * 8;
        bf16x8 a[4];
        #pragma unroll
        for (int ks = 0; ks < 4; ++ks) a[ks] = ldfrag(Ag + ks * 32);

        #pragma unroll
        for (int nt = 0; nt < 4; ++nt) {
            int np = nt * 16 + r16;
            const unsigned short* Bg = wsb + W3B_OFF + (j * 64 + np) * 128 + kb * 8;
            bf16x8 b[4];
            #pragma unroll
            for (int ks = 0; ks < 4; ++ks) b[ks] = ldfrag(Bg + ks * 32);
            f32x4 acc = {};
            #pragma unroll
            for (int ks = 0; ks < 4; ++ks)
                acc = __builtin_amdgcn_mfma_f32_16x16x32_bf16(a[ks], b[ks], acc, 0, 0, 0);
            #pragma unroll
            for (int rr = 0; rr < 4; ++rr) {
                int e = crow + rr;
                float v = bf2f(Vg[(e0 + e) * 512 + j * 64 + np]);
                float sv = sg1[e * 9 + j];
                oacc[nt][rr] += sv * v + (1.f - v * v) * acc[rr];
            }
        }
    }

    #pragma unroll
    for (int nt = 0; nt < 4; ++nt) {
        int np = nt * 16 + r16;
        #pragma unroll
        for (int rr = 0; rr < 4; ++rr)
            part[(w * 16 + crow + rr) * 64 + np] = oacc[nt][rr];
    }
    __syncthreads();
    {
        int e = tid >> 4, c4 = (tid & 15) * 4;
        float4 s = {0.f, 0.f, 0.f, 0.f};
        #pragma unroll
        for (int w4 = 0; w4 < 4; ++w4) {
            float4 p = *reinterpret_cast<const float4*>(&part[(w4 * 16 + e) * 64 + c4]);
            s.x += p.x; s.y += p.y; s.z += p.z; s.w += p.w;
        }
        *reinterpret_cast<float4*>(&out[(e0 + e) * 64 + c4]) = s;
    }
}

extern "C" void kernel_launch(void* const* d_in, const int* in_sizes, int n_in,
                              void* d_out, int out_size, void* d_ws, size_t ws_size,
                              hipStream_t stream) {
    const float* hg  = (const float*)d_in[0];
    const float* sg  = (const float*)d_in[1];
    const float* W1  = (const float*)d_in[2];
    const float* b1  = (const float*)d_in[3];
    const float* W2  = (const float*)d_in[4];
    const float* b2  = (const float*)d_in[5];
    const float* W3  = (const float*)d_in[6];
    const float* b3  = (const float*)d_in[7];
    float* outp = (float*)d_out;
    unsigned short* wsb = (unsigned short*)d_ws;

    hipLaunchKernelGGL(prep_weights, dim3((WS_WEIGHTS + 255) / 256), dim3(256), 0, stream,
                       W1, W2, W3, wsb);
    hipLaunchKernelGGL(k12_fwd, dim3(NEL / 16), dim3(256), 0, stream, hg, b1, b2, b3, wsb);
    hipLaunchKernelGGL(k3_jvp12, dim3(NEL / 8), dim3(256), 0, stream, sg, wsb);
    hipLaunchKernelGGL(k4_jvp3, dim3(NEL / 16), dim3(256), 0, stream, sg, wsb, outp);
}

// Round 24
// 71.312 us; speedup vs baseline: 1.0757x; 1.0757x over previous
//
#include <hip/hip_runtime.h>
#include <hip/hip_bf16.h>

#define NEL 16384

// ---- workspace layout (offsets in SHORTS from d_ws base) ----
#define W1B_OFF 0                         // bf16 W1 [128][64]
#define W2B_OFF 8192                      // bf16 W2 [128][128]
#define W3B_OFF 24576                     // bf16 W3 [512][128]
#define WS_WEIGHTS 90112
#define S1_OFF  90112                     // bf16 [NEL][128]
#define S2_OFF  (S1_OFF + NEL*128)
#define Z2_OFF  (S2_OFF + NEL*128)        // (unused slot, kept for layout stability)
#define V_OFF   (Z2_OFF + NEL*128)        // bf16 [NEL][512]
#define DZ2_OFF (V_OFF + NEL*512)         // bf16 [NEL*8][128]  (row m = e*8+j)

typedef __attribute__((ext_vector_type(8))) short bf16x8;
typedef __attribute__((ext_vector_type(4))) float f32x4;

__device__ __forceinline__ float bf2f(unsigned int u16) {
    unsigned int x = u16 << 16;
    float f; __builtin_memcpy(&f, &x, 4); return f;
}
__device__ __forceinline__ unsigned short f2bf(float f) {
    unsigned int x; __builtin_memcpy(&x, &f, 4);
    x = (x + 0x7FFFu + ((x >> 16) & 1u)) >> 16;
    return (unsigned short)x;
}
__device__ __forceinline__ void unpack8(uint4 q, float* f) {
    f[0] = bf2f(q.x & 0xFFFFu); f[1] = bf2f(q.x >> 16);
    f[2] = bf2f(q.y & 0xFFFFu); f[3] = bf2f(q.y >> 16);
    f[4] = bf2f(q.z & 0xFFFFu); f[5] = bf2f(q.z >> 16);
    f[6] = bf2f(q.w & 0xFFFFu); f[7] = bf2f(q.w >> 16);
}
__device__ __forceinline__ void sp_sig(float x, float& sp, float& sig) {
    float t = __expf(-fabsf(x));
    float r = __builtin_amdgcn_rcpf(1.f + t);
    sig = (x >= 0.f) ? r : 1.f - r;
    sp  = fmaxf(x, 0.f) + __logf(1.f + t);
}
__device__ __forceinline__ float tanh_fast(float x) {
    float t = __expf(-2.f * fabsf(x));
    float y = (1.f - t) * __builtin_amdgcn_rcpf(1.f + t);
    unsigned int xb, yb;
    __builtin_memcpy(&xb, &x, 4);
    __builtin_memcpy(&yb, &y, 4);
    yb |= (xb & 0x80000000u);
    float rr; __builtin_memcpy(&rr, &yb, 4);
    return rr;
}
__device__ __forceinline__ bf16x8 ldfrag(const unsigned short* p) {
    return *reinterpret_cast<const bf16x8*>(p);
}
__device__ __forceinline__ void cpu4(unsigned short* dst, const unsigned short* src) {
    *reinterpret_cast<uint4*>(dst) = *reinterpret_cast<const uint4*>(src);
}

// ---- prep: bf16 copies of W1, W2, W3 in [out][k] layout ----
__global__ void prep_weights(const float* __restrict__ W1,
                             const float* __restrict__ W2,
                             const float* __restrict__ W3,
                             unsigned short* __restrict__ wb) {
    int i = blockIdx.x * blockDim.x + threadIdx.x;
    if (i >= WS_WEIGHTS) return;
    float v;
    if (i < W2B_OFF) v = W1[i];
    else if (i < W3B_OFF) v = W2[i - W2B_OFF];
    else v = W3[i - W3B_OFF];
    wb[i] = f2bf(v);
}

// ============ K12: fwd1 + fwd2 (staged) + fwd3 (DOUBLE-BUFFERED 8x64-col chunks) ============
// 16 elems/block, grid 1024, 4 blocks/CU. LDS 39168 B.
#define K12_LDS 39168
__global__ __launch_bounds__(256, 4)
void k12_fwd(const float* __restrict__ hg,
             const float* __restrict__ b1,
             const float* __restrict__ b2,
             const float* __restrict__ b3,
             unsigned short* __restrict__ wsb) {
    __shared__ __align__(16) char sm[K12_LDS];
    unsigned short* w1s  = (unsigned short*)(sm);           // [128][72]  phase1
    unsigned short* hs   = (unsigned short*)(sm + 18432);   // [16][72]   phase1
    unsigned short* w2s  = (unsigned short*)(sm);           // [128][136] phase2 (overlay)
    unsigned short* wcb0 = (unsigned short*)(sm);           // [64][136]  fwd3 dbuf 0
    unsigned short* wcb1 = (unsigned short*)(sm + 17408);   // [64][136]  fwd3 dbuf 1
    unsigned short* z1s  = (unsigned short*)(sm + 34816);   // [16][136]
    unsigned short* z2s  = (unsigned short*)(sm + 34816);   // [16][136] overlays z1s
    unsigned short* S1g = wsb + S1_OFF;
    unsigned short* S2g = wsb + S2_OFF;
    unsigned short* Vg  = wsb + V_OFF;

    const int tid = threadIdx.x;
    const int e0 = blockIdx.x * 16;
    const int lane = tid & 63;
    const int w = tid >> 6;
    const int r16 = lane & 15;
    const int kb = lane >> 4;
    const int crow = kb * 4;

    #pragma unroll
    for (int q = 0; q < 4; ++q) {
        int idx = q * 256 + tid;
        int row = idx >> 3, u4 = idx & 7;
        cpu4(&w1s[row * 72 + u4 * 8], &wsb[W1B_OFF + row * 64 + u4 * 8]);
    }
    {
        int row = tid >> 4, f4 = tid & 15;
        float4 hv = *reinterpret_cast<const float4*>(&hg[(e0 + row) * 64 + f4 * 4]);
        ushort2 lo = { f2bf(hv.x), f2bf(hv.y) };
        ushort2 hi = { f2bf(hv.z), f2bf(hv.w) };
        *reinterpret_cast<ushort2*>(&hs[row * 72 + f4 * 4]) = lo;
        *reinterpret_cast<ushort2*>(&hs[row * 72 + f4 * 4 + 2]) = hi;
    }
    __syncthreads();

    // fwd1: M=16 N=128 K=64
    {
        const unsigned short* Ab = hs + r16 * 72 + kb * 8;
        bf16x8 a0 = ldfrag(Ab), a1 = ldfrag(Ab + 32);
        f32x4 acc[2] = {};
        #pragma unroll
        for (int t = 0; t < 2; ++t) {
            int col16 = (w * 2 + t) * 16 + r16;
            const unsigned short* Bb = w1s + col16 * 72 + kb * 8;
            acc[t] = __builtin_amdgcn_mfma_f32_16x16x32_bf16(a0, ldfrag(Bb), acc[t], 0, 0, 0);
            acc[t] = __builtin_amdgcn_mfma_f32_16x16x32_bf16(a1, ldfrag(Bb + 32), acc[t], 0, 0, 0);
        }
        #pragma unroll
        for (int t = 0; t < 2; ++t) {
            int col = (w * 2 + t) * 16 + r16;
            float bb = b1[col];
            #pragma unroll
            for (int rr = 0; rr < 4; ++rr) {
                int e = crow + rr;
                float sp, sg;
                sp_sig(acc[t][rr] + bb, sp, sg);
                z1s[e * 136 + col] = f2bf(sp);
                S1g[(e0 + e) * 128 + col] = f2bf(sg);
            }
        }
    }
    __syncthreads();

    #pragma unroll
    for (int q = 0; q < 8; ++q) {
        int idx = q * 256 + tid;
        int row = idx >> 4, u4 = idx & 15;
        cpu4(&w2s[row * 136 + u4 * 8], &wsb[W2B_OFF + row * 128 + u4 * 8]);
    }
    __syncthreads();

    // fwd2: race-protected overlay (A-frags held in regs behind barrier)
    {
        const unsigned short* Ab = z1s + r16 * 136 + kb * 8;
        bf16x8 a[4];
        #pragma unroll
        for (int ks = 0; ks < 4; ++ks) a[ks] = ldfrag(Ab + ks * 32);
        __syncthreads();
        f32x4 acc[2] = {};
        #pragma unroll
        for (int t = 0; t < 2; ++t) {
            int col16 = (w * 2 + t) * 16 + r16;
            const unsigned short* Bb = w2s + col16 * 136 + kb * 8;
            #pragma unroll
            for (int ks = 0; ks < 4; ++ks)
                acc[t] = __builtin_amdgcn_mfma_f32_16x16x32_bf16(a[ks], ldfrag(Bb + ks * 32), acc[t], 0, 0, 0);
        }
        #pragma unroll
        for (int t = 0; t < 2; ++t) {
            int col = (w * 2 + t) * 16 + r16;
            float bb = b2[col];
            #pragma unroll
            for (int rr = 0; rr < 4; ++rr) {
                int e = crow + rr;
                float sp, sg;
                sp_sig(acc[t][rr] + bb, sp, sg);
                z2s[e * 136 + col] = f2bf(sp);
                S2g[(e0 + e) * 128 + col] = f2bf(sg);
            }
        }
    }
    __syncthreads();   // z2s complete; all w2s reads done

    // fwd3: 8 chunks of 64 cols, double-buffered W3 staging (stage c+1 overlaps compute c)
    {
        #pragma unroll
        for (int q = 0; q < 4; ++q) {
            int idx = q * 256 + tid;
            int row = idx >> 4, u4 = idx & 15;
            cpu4(&wcb0[row * 136 + u4 * 8], &wsb[W3B_OFF + row * 128 + u4 * 8]);
        }
        __syncthreads();

        const unsigned short* Ab = z2s + r16 * 136 + kb * 8;
        bf16x8 a[4];
        #pragma unroll
        for (int ks = 0; ks < 4; ++ks) a[ks] = ldfrag(Ab + ks * 32);

        for (int c = 0; c < 8; ++c) {
            unsigned short* cur = (c & 1) ? wcb1 : wcb0;
            unsigned short* nxt = (c & 1) ? wcb0 : wcb1;
            if (c < 7) {
                #pragma unroll
                for (int q = 0; q < 4; ++q) {
                    int idx = q * 256 + tid;
                    int row = idx >> 4, u4 = idx & 15;
                    cpu4(&nxt[row * 136 + u4 * 8], &wsb[W3B_OFF + ((c + 1) * 64 + row) * 128 + u4 * 8]);
                }
            }
            int col = c * 64 + w * 16 + r16;
            const unsigned short* Bb = cur + (w * 16 + r16) * 136 + kb * 8;
            f32x4 acc = {};
            #pragma unroll
            for (int ks = 0; ks < 4; ++ks)
                acc = __builtin_amdgcn_mfma_f32_16x16x32_bf16(a[ks], ldfrag(Bb + ks * 32), acc, 0, 0, 0);
            float bb = b3[col];
            #pragma unroll
            for (int rr = 0; rr < 4; ++rr) {
                int e = crow + rr;
                Vg[(e0 + e) * 512 + col] = f2bf(tanh_fast(acc[rr] + bb));
            }
            __syncthreads();   // cur reads done before it is restaged; nxt visible for c+1
        }
    }
}

// ============ K3: T-build + jvp1 + jvp2 (R18/R14 proven: staged W2 halves, 35968 B, 4/CU) ============
#define K3_LDS 35968
__global__ __launch_bounds__(256, 4)
void k3_jvp12(const float* __restrict__ sigg,
              unsigned short* __restrict__ wsb) {
    __shared__ __align__(16) char sm[K3_LDS];
    unsigned short* w1s  = (unsigned short*)(sm);           // [128][72]   phase A
    unsigned short* ts   = (unsigned short*)(sm + 18432);   // [64][72]    phase A
    float*          sigsm= (float*)(sm + 34816);            // [288]       phase A
    unsigned short* dz1s = (unsigned short*)(sm);           // [64][136]   phase B
    unsigned short* w2sh = (unsigned short*)(sm + 17408);   // [64][136]   phase B (half)
    const unsigned short* S1g = wsb + S1_OFF;
    const unsigned short* S2g = wsb + S2_OFF;
    const unsigned short* Vg  = wsb + V_OFF;
    unsigned short* DZ2g = wsb + DZ2_OFF;

    const int tid = threadIdx.x;
    const int e0 = blockIdx.x * 8;
    const int lane = tid & 63;
    const int w = tid >> 6;
    const int r16 = lane & 15;
    const int kb = lane >> 4;

    #pragma unroll
    for (int q = 0; q < 4; ++q) {
        int idx = q * 256 + tid;
        int row = idx >> 3, u4 = idx & 7;
        cpu4(&w1s[row * 72 + u4 * 8], &wsb[W1B_OFF + row * 64 + u4 * 8]);
    }
    #pragma unroll
    for (int q = 0; q < 2; ++q) {
        int idx = q * 256 + tid;
        if (idx < 288) sigsm[idx] = sigg[e0 * 36 + idx];
    }
    __syncthreads();   // B1

    // T-build: V direct from global
    {
        int m = tid >> 2, kq = tid & 3;
        int e = m >> 3, j = m & 7;
        float c8[8];
        #pragma unroll
        for (int i = 0; i < 8; ++i) {
            float v = 0.f;
            if (i < j) {
                int p = 7 * i - i * (i - 1) / 2 + (j - i - 1);
                v = sigsm[e * 36 + 8 + p];
            } else if (i > j) {
                int p = 7 * j - j * (j - 1) / 2 + (i - j - 1);
                v = -sigsm[e * 36 + 8 + p];
            }
            c8[i] = v;
        }
        const unsigned short* Vrow = &Vg[(e0 + e) * 512 + kq * 16];
        float acc[16] = {};
        #pragma unroll
        for (int i = 0; i < 8; ++i) {
            uint4 qa = *reinterpret_cast<const uint4*>(Vrow + i * 64);
            uint4 qb = *reinterpret_cast<const uint4*>(Vrow + i * 64 + 8);
            float fa[8], fb[8];
            unpack8(qa, fa); unpack8(qb, fb);
            #pragma unroll
            for (int kk = 0; kk < 8; ++kk) {
                acc[kk]     += c8[i] * fa[kk];
                acc[kk + 8] += c8[i] * fb[kk];
            }
        }
        unsigned short o[16];
        #pragma unroll
        for (int kk = 0; kk < 16; ++kk) o[kk] = f2bf(acc[kk]);
        uint4 qo;
        qo.x = (unsigned int)o[0] | ((unsigned int)o[1] << 16);
        qo.y = (unsigned int)o[2] | ((unsigned int)o[3] << 16);
        qo.z = (unsigned int)o[4] | ((unsigned int)o[5] << 16);
        qo.w = (unsigned int)o[6] | ((unsigned int)o[7] << 16);
        *reinterpret_cast<uint4*>(&ts[m * 72 + kq * 16]) = qo;
        qo.x = (unsigned int)o[8]  | ((unsigned int)o[9]  << 16);
        qo.y = (unsigned int)o[10] | ((unsigned int)o[11] << 16);
        qo.z = (unsigned int)o[12] | ((unsigned int)o[13] << 16);
        qo.w = (unsigned int)o[14] | ((unsigned int)o[15] << 16);
        *reinterpret_cast<uint4*>(&ts[m * 72 + kq * 16 + 8]) = qo;
    }
    __syncthreads();   // B2

    // jvp1 -> registers
    float dz1v[8][4];
    const int rbase = w * 16 + kb * 4;
    const int e_loc = rbase >> 3;
    {
        const unsigned short* Ab = ts + (w * 16 + r16) * 72 + kb * 8;
        bf16x8 a0 = ldfrag(Ab), a1 = ldfrag(Ab + 32);
        f32x4 acc[8] = {};
        #pragma unroll
        for (int nt = 0; nt < 8; ++nt) {
            const unsigned short* Bb = w1s + (nt * 16 + r16) * 72 + kb * 8;
            acc[nt] = __builtin_amdgcn_mfma_f32_16x16x32_bf16(a0, ldfrag(Bb), acc[nt], 0, 0, 0);
            acc[nt] = __builtin_amdgcn_mfma_f32_16x16x32_bf16(a1, ldfrag(Bb + 32), acc[nt], 0, 0, 0);
        }
        #pragma unroll
        for (int nt = 0; nt < 8; ++nt) {
            int col = nt * 16 + r16;
            float s1v = bf2f(S1g[(e0 + e_loc) * 128 + col]);
            #pragma unroll
            for (int rr = 0; rr < 4; ++rr)
                dz1v[nt][rr] = acc[nt][rr] * s1v;
        }
    }
    __syncthreads();   // B3

    // Phase B: write dz1s; stage W2 half 0
    #pragma unroll
    for (int nt = 0; nt < 8; ++nt) {
        int col = nt * 16 + r16;
        #pragma unroll
        for (int rr = 0; rr < 4; ++rr)
            dz1s[(rbase + rr) * 136 + col] = f2bf(dz1v[nt][rr]);
    }
    #pragma unroll
    for (int q = 0; q < 4; ++q) {
        int idx = q * 256 + tid;
        int row = idx >> 4, u4 = idx & 15;
        cpu4(&w2sh[row * 136 + u4 * 8], &wsb[W2B_OFF + row * 128 + u4 * 8]);
    }
    __syncthreads();   // B4

    bf16x8 a2[4];
    {
        const unsigned short* Ab = dz1s + (w * 16 + r16) * 136 + kb * 8;
        #pragma unroll
        for (int ks = 0; ks < 4; ++ks) a2[ks] = ldfrag(Ab + ks * 32);
    }

    // jvp2 half 0
    {
        f32x4 acc[4] = {};
        #pragma unroll
        for (int nt = 0; nt < 4; ++nt) {
            const unsigned short* Bb = w2sh + (nt * 16 + r16) * 136 + kb * 8;
            #pragma unroll
            for (int ks = 0; ks < 4; ++ks)
                acc[nt] = __builtin_amdgcn_mfma_f32_16x16x32_bf16(a2[ks], ldfrag(Bb + ks * 32), acc[nt], 0, 0, 0);
        }
        #pragma unroll
        for (int nt = 0; nt < 4; ++nt) {
            int col = nt * 16 + r16;
            float s2v = bf2f(S2g[(e0 + e_loc) * 128 + col]);
            #pragma unroll
            for (int rr = 0; rr < 4; ++rr)
                DZ2g[(e0 * 8 + rbase + rr) * 128 + col] = f2bf(acc[nt][rr] * s2v);
        }
    }
    __syncthreads();   // B5

    #pragma unroll
    for (int q = 0; q < 4; ++q) {
        int idx = q * 256 + tid;
        int row = idx >> 4, u4 = idx & 15;
        cpu4(&w2sh[row * 136 + u4 * 8], &wsb[W2B_OFF + (64 + row) * 128 + u4 * 8]);
    }
    __syncthreads();   // B6

    // jvp2 half 1
    {
        f32x4 acc[4] = {};
        #pragma unroll
        for (int nt = 0; nt < 4; ++nt) {
            const unsigned short* Bb = w2sh + (nt * 16 + r16) * 136 + kb * 8;
            #pragma unroll
            for (int ks = 0; ks < 4; ++ks)
                acc[nt] = __builtin_amdgcn_mfma_f32_16x16x32_bf16(a2[ks], ldfrag(Bb + ks * 32), acc[nt], 0, 0, 0);
        }
        #pragma unroll
        for (int nt = 0; nt < 4; ++nt) {
            int col = 64 + nt * 16 + r16;
            float s2v = bf2f(S2g[(e0 + e_loc) * 128 + col]);
            #pragma unroll
            for (int rr = 0; rr < 4; ++rr)
                DZ2g[(e0 * 8 + rbase + rr) * 128 + col] = f2bf(acc[nt][rr] * s2v);
        }
    }
}

// ============ K4: jvp3, WAVE-AUTONOMOUS (j = w, w+4), barrier-free loop (R18 proven) ============
#define K4_LDS (16384 + 576)
__global__ __launch_bounds__(256, 4)
void k4_jvp3(const float* __restrict__ sigg,
             const unsigned short* __restrict__ wsb,
             float* __restrict__ out) {
    __shared__ __align__(16) char sm[K4_LDS];
    float* part = (float*)sm;               // [4][16][64]
    float* sg1  = (float*)(sm + 16384);     // [16][9]
    const unsigned short* Vg = wsb + V_OFF;
    const unsigned short* DZ2g = wsb + DZ2_OFF;

    const int tid = threadIdx.x;
    const int e0 = blockIdx.x * 16;
    const int lane = tid & 63;
    const int w = tid >> 6;
    const int r16 = lane & 15;
    const int kb = lane >> 4;
    const int crow = kb * 4;

    if (tid < 128) {
        int e = tid >> 3, j7 = tid & 7;
        sg1[e * 9 + j7] = sigg[(e0 + e) * 36 + j7];
    }
    __syncthreads();

    float oacc[4][4] = {};

    #pragma unroll
    for (int jj = 0; jj < 2; ++jj) {
        int j = w + jj * 4;
        const unsigned short* Ag = DZ2g + ((e0 + r16) * 8 + j) * 128 + kb * 8;
        bf16x8 a[4];
        #pragma unroll
        for (int ks = 0; ks < 4; ++ks) a[ks] = ldfrag(Ag + ks * 32);

        #pragma unroll
        for (int nt = 0; nt < 4; ++nt) {
            int np = nt * 16 + r16;
            const unsigned short* Bg = wsb + W3B_OFF + (j * 64 + np) * 128 + kb * 8;
            bf16x8 b[4];
            #pragma unroll
            for (int ks = 0; ks < 4; ++ks) b[ks] = ldfrag(Bg + ks * 32);
            f32x4 acc = {};
            #pragma unroll
            for (int ks = 0; ks < 4; ++ks)
                acc = __builtin_amdgcn_mfma_f32_16x16x32_bf16(a[ks], b[ks], acc, 0, 0, 0);
            #pragma unroll
            for (int rr = 0; rr < 4; ++rr) {
                int e = crow + rr;
                float v = bf2f(Vg[(e0 + e) * 512 + j * 64 + np]);
                float sv = sg1[e * 9 + j];
                oacc[nt][rr] += sv * v + (1.f - v * v) * acc[rr];
            }
        }
    }

    #pragma unroll
    for (int nt = 0; nt < 4; ++nt) {
        int np = nt * 16 + r16;
        #pragma unroll
        for (int rr = 0; rr < 4; ++rr)
            part[(w * 16 + crow + rr) * 64 + np] = oacc[nt][rr];
    }
    __syncthreads();
    {
        int e = tid >> 4, c4 = (tid & 15) * 4;
        float4 s = {0.f, 0.f, 0.f, 0.f};
        #pragma unroll
        for (int w4 = 0; w4 < 4; ++w4) {
            float4 p = *reinterpret_cast<const float4*>(&part[(w4 * 16 + e) * 64 + c4]);
            s.x += p.x; s.y += p.y; s.z += p.z; s.w += p.w;
        }
        *reinterpret_cast<float4*>(&out[(e0 + e) * 64 + c4]) = s;
    }
}

extern "C" void kernel_launch(void* const* d_in, const int* in_sizes, int n_in,
                              void* d_out, int out_size, void* d_ws, size_t ws_size,
                              hipStream_t stream) {
    const float* hg  = (const float*)d_in[0];
    const float* sg  = (const float*)d_in[1];
    const float* W1  = (const float*)d_in[2];
    const float* b1  = (const float*)d_in[3];
    const float* W2  = (const float*)d_in[4];
    const float* b2  = (const float*)d_in[5];
    const float* W3  = (const float*)d_in[6];
    const float* b3  = (const float*)d_in[7];
    float* outp = (float*)d_out;
    unsigned short* wsb = (unsigned short*)d_ws;

    hipLaunchKernelGGL(prep_weights, dim3((WS_WEIGHTS + 255) / 256), dim3(256), 0, stream,
                       W1, W2, W3, wsb);
    hipLaunchKernelGGL(k12_fwd, dim3(NEL / 16), dim3(256), 0, stream, hg, b1, b2, b3, wsb);
    hipLaunchKernelGGL(k3_jvp12, dim3(NEL / 8), dim3(256), 0, stream, sg, wsb);
    hipLaunchKernelGGL(k4_jvp3, dim3(NEL / 16), dim3(256), 0, stream, sg, wsb, outp);
}